// Round 4
// baseline (137.655 us; speedup 1.0000x reference)
//
#include <hip/hip_runtime.h>
#include <math.h>

// CapsuleLayer dynamic routing, factored (u_hat never materialized):
//   s[b,m,:] = ((Sum_n e_n in[b,n,:]) / Sum_n e_n) @ W[:,m,:],  e_n = exp(logit)
//   logit[n,m] after pass p = in[b,n,:] . cum_wv[m,:]  (logits linear in wv ->
//   cumulative wv in LDS, NO per-n state). Pass 0 (uniform) = column sum, e=1.
//
// Grid 1024 = 64 b x 16 m-pairs; 512 thr (8 waves); __launch_bounds__(512,8)
// -> 4 blocks/CU = 32 waves/CU (100%) PROVIDED no spill: persistent lane state
// is wv(16) + xc(16) + S only; loads consumed directly (no repack arrays),
// k-loop NOT unrolled (TLP, not ILP, hides L2 latency).
// Lane l: m = m0 + (l&1), row-group l>>1 (pair shares 64B row -> coalesced);
// butterfly reduction 17 values x 5 stages (masks 2..32).
// b = bx&63 pins all 16 blocks of batch b to XCD b%8 (1 MB hot per L2).

#define TPB 512

__global__ __launch_bounds__(TPB, 8)
void capsule_routing_kernel(const float* __restrict__ in,
                            const float* __restrict__ W,
                            float* __restrict__ out)
{
    __shared__ float red[8 * 34];    // [wave][mi*17 + {S, xc[16]}]
    __shared__ float fin[34];
    __shared__ float cum[32];        // cumulative wv[mi][d]
    __shared__ float w_lds[16 * 33]; // W[d][mi*16+c], stride 33 (conflict-free)

    const int tid = threadIdx.x;
    const int w   = tid >> 6;
    const int l   = tid & 63;
    const int mi  = l & 1;
    const int rg  = l >> 1;                    // 0..31
    const int b   = blockIdx.x & 63;
    const int m0  = (blockIdx.x >> 6) << 1;

    const float* __restrict__ inb = in + ((size_t)b << 15);  // b*2048*16

    // stage W[:, m0:m0+2, :] -> LDS (512 floats, one per thread)
    {
        const int d = tid >> 5, r = tid & 31;
        w_lds[d * 33 + r] = W[(d << 9) + (m0 << 4) + r];
    }
    __syncthreads();

    for (int pass = 0; pass < 3; ++pass) {
        float4 wv0, wv1, wv2, wv3;
        if (pass) {
            const float* c = &cum[mi << 4];    // 2-addr broadcast reads: free
            wv0 = make_float4(c[0],  c[1],  c[2],  c[3]);
            wv1 = make_float4(c[4],  c[5],  c[6],  c[7]);
            wv2 = make_float4(c[8],  c[9],  c[10], c[11]);
            wv3 = make_float4(c[12], c[13], c[14], c[15]);
        }

        float S = 0.f;
        float4 x0 = make_float4(0.f, 0.f, 0.f, 0.f);
        float4 x1 = x0, x2 = x0, x3 = x0;

        const float4* __restrict__ p =
            (const float4*)inb + (((w << 5) + rg) << 2);

        #pragma unroll 1
        for (int k = 0; k < 8; ++k) {
            const float4 f0 = p[0];
            const float4 f1 = p[1];
            const float4 f2 = p[2];
            const float4 f3 = p[3];
            p += 1024;                          // 256 rows * 4 float4
            if (pass) {
                float dx = f0.x * wv0.x + f1.x * wv1.x + f2.x * wv2.x + f3.x * wv3.x;
                float dy = f0.y * wv0.y + f1.y * wv1.y + f2.y * wv2.y + f3.y * wv3.y;
                float dz = f0.z * wv0.z + f1.z * wv1.z + f2.z * wv2.z + f3.z * wv3.z;
                float dw = f0.w * wv0.w + f1.w * wv1.w + f2.w * wv2.w + f3.w * wv3.w;
                const float e = __expf((dx + dy) + (dz + dw));  // |logit| small
                S += e;
                x0.x += e * f0.x; x0.y += e * f0.y; x0.z += e * f0.z; x0.w += e * f0.w;
                x1.x += e * f1.x; x1.y += e * f1.y; x1.z += e * f1.z; x1.w += e * f1.w;
                x2.x += e * f2.x; x2.y += e * f2.y; x2.z += e * f2.z; x2.w += e * f2.w;
                x3.x += e * f3.x; x3.y += e * f3.y; x3.z += e * f3.z; x3.w += e * f3.w;
            } else {                            // uniform pass: e = 1
                x0.x += f0.x; x0.y += f0.y; x0.z += f0.z; x0.w += f0.w;
                x1.x += f1.x; x1.y += f1.y; x1.z += f1.z; x1.w += f1.w;
                x2.x += f2.x; x2.y += f2.y; x2.z += f2.z; x2.w += f2.w;
                x3.x += f3.x; x3.y += f3.y; x3.z += f3.z; x3.w += f3.w;
            }
        }
        if (!pass) S = 8.f;                     // 8 rows/lane, e=1

        // butterfly over the 32 lanes sharing this mi (masks 2..32)
        #pragma unroll
        for (int mask = 2; mask <= 32; mask <<= 1) {
            S    += __shfl_xor(S,    mask);
            x0.x += __shfl_xor(x0.x, mask); x0.y += __shfl_xor(x0.y, mask);
            x0.z += __shfl_xor(x0.z, mask); x0.w += __shfl_xor(x0.w, mask);
            x1.x += __shfl_xor(x1.x, mask); x1.y += __shfl_xor(x1.y, mask);
            x1.z += __shfl_xor(x1.z, mask); x1.w += __shfl_xor(x1.w, mask);
            x2.x += __shfl_xor(x2.x, mask); x2.y += __shfl_xor(x2.y, mask);
            x2.z += __shfl_xor(x2.z, mask); x2.w += __shfl_xor(x2.w, mask);
            x3.x += __shfl_xor(x3.x, mask); x3.y += __shfl_xor(x3.y, mask);
            x3.z += __shfl_xor(x3.z, mask); x3.w += __shfl_xor(x3.w, mask);
        }
        if (l < 2) {                            // l == mi
            float* rp = &red[w * 34 + l * 17];
            rp[0]  = S;
            rp[1]  = x0.x; rp[2]  = x0.y; rp[3]  = x0.z; rp[4]  = x0.w;
            rp[5]  = x1.x; rp[6]  = x1.y; rp[7]  = x1.z; rp[8]  = x1.w;
            rp[9]  = x2.x; rp[10] = x2.y; rp[11] = x2.z; rp[12] = x2.w;
            rp[13] = x3.x; rp[14] = x3.y; rp[15] = x3.z; rp[16] = x3.w;
        }
        __syncthreads();
        if (tid < 34) {
            float a = 0.f;
            #pragma unroll
            for (int w2 = 0; w2 < 8; ++w2) a += red[w2 * 34 + tid];
            fin[tid] = a;
        }
        __syncthreads();

        // tail: s = (xc/S) @ W_m, v = squash(s); update cum or write out
        if (tid < 32) {
            const int tmi = tid >> 4;
            const int tc  = tid & 15;
            const float rS = 1.f / fin[tmi * 17];
            float s = 0.f;
            #pragma unroll
            for (int d = 0; d < 16; ++d)
                s += fin[tmi * 17 + 1 + d] * w_lds[d * 33 + (tmi << 4) + tc];
            s *= rS;
            float n2 = s * s;
            n2 += __shfl_xor(n2, 1);
            n2 += __shfl_xor(n2, 2);
            n2 += __shfl_xor(n2, 4);
            n2 += __shfl_xor(n2, 8);
            const float nr = sqrtf(n2);
            const float v  = s * (n2 / (1.f + n2)) / (nr + 1e-7f);
            if (pass < 2) {
                float wvv = 0.f;                // wv[d=tc] for capsule tmi
                #pragma unroll
                for (int c2 = 0; c2 < 16; ++c2)
                    wvv += w_lds[tc * 33 + (tmi << 4) + c2] * __shfl(v, (tmi << 4) + c2);
                if (pass == 0) cum[(tmi << 4) + tc] = wvv;
                else           cum[(tmi << 4) + tc] += wvv;
            } else {
                out[((size_t)b << 9) + ((m0 + tmi) << 4) + tc] = v;
            }
        }
        __syncthreads();
    }
}

extern "C" void kernel_launch(void* const* d_in, const int* in_sizes, int n_in,
                              void* d_out, int out_size, void* d_ws, size_t ws_size,
                              hipStream_t stream) {
    (void)in_sizes; (void)n_in; (void)d_ws; (void)ws_size; (void)out_size;
    const float* in = (const float*)d_in[0];
    const float* W  = (const float*)d_in[1];
    float* out = (float*)d_out;
    hipLaunchKernelGGL(capsule_routing_kernel, dim3(1024), dim3(TPB), 0, stream,
                       in, W, out);
}

// Round 5
// 100.202 us; speedup vs baseline: 1.3738x; 1.3738x over previous
//
#include <hip/hip_runtime.h>
#include <math.h>

// CapsuleLayer dynamic routing, factored (u_hat never materialized):
//   s[b,m,:] = ((Sum_n e_n in[b,n,:]) / Sum_n e_n) @ W[:,m,:],  e_n = exp(logit)
//   logit[n,m] after pass p = in[b,n,:] . cum_wv[m,:]  (logits linear in wv ->
//   cumulative wv in LDS, NO per-n state). Pass 0 (uniform) = column sum, e=1.
//
// Grid 1024 = 64 b x 16 m-pairs; 512 thr (8 waves).
// TOOLCHAIN RULE (measured R1/R2/R3+R4): this compiler allocates
// VGPR = 256 / launch_bounds_min_waves_per_EU. (512,8) -> 32 regs -> massive
// spill (182 MB scratch writes, 83 us). (512,4) -> 64 regs -> fits (R2-proven),
// and HARDWARE occupancy at vgpr<=64 is still 8 waves/EU = 32 waves/CU (m69),
// since occupancy follows the actual VGPR count, not the declaration.
// Lane l: m = m0 + (l&1), row l>>1 (pair shares 64B row -> coalescer merges);
// butterfly reduction 17 values x 5 stages (masks 2..32).
// b = bx&63 pins all 16 blocks of batch b to XCD b%8 (128 KB hot per L2).

#define TPB 512

__global__ __launch_bounds__(TPB, 4)   // VGPR budget 64; HW still runs 8 waves/EU
void capsule_routing_kernel(const float* __restrict__ in,
                            const float* __restrict__ W,
                            float* __restrict__ out)
{
    __shared__ float red[8 * 34];    // [wave][mi*17 + {S, xc[16]}]
    __shared__ float fin[34];
    __shared__ float cum[32];        // cumulative wv[mi][d]
    __shared__ float w_lds[16 * 33]; // W[d][mi*16+c], stride 33 (conflict-free)

    const int tid = threadIdx.x;
    const int w   = tid >> 6;
    const int l   = tid & 63;
    const int mi  = l & 1;
    const int rg  = l >> 1;                    // 0..31
    const int b   = blockIdx.x & 63;
    const int m0  = (blockIdx.x >> 6) << 1;

    const float* __restrict__ inb = in + ((size_t)b << 15);  // b*2048*16

    // stage W[:, m0:m0+2, :] -> LDS (512 floats, one per thread)
    {
        const int d = tid >> 5, r = tid & 31;
        w_lds[d * 33 + r] = W[(d << 9) + (m0 << 4) + r];
    }
    __syncthreads();

    for (int pass = 0; pass < 3; ++pass) {
        float4 wv0, wv1, wv2, wv3;
        if (pass) {
            const float* c = &cum[mi << 4];    // broadcast-ish reads: cheap
            wv0 = make_float4(c[0],  c[1],  c[2],  c[3]);
            wv1 = make_float4(c[4],  c[5],  c[6],  c[7]);
            wv2 = make_float4(c[8],  c[9],  c[10], c[11]);
            wv3 = make_float4(c[12], c[13], c[14], c[15]);
        }

        float S = 0.f;
        float4 x0 = make_float4(0.f, 0.f, 0.f, 0.f);
        float4 x1 = x0, x2 = x0, x3 = x0;

        // rows covered by this lane: (w*32 + rg) + 256*k, k=0..7
        const float4* __restrict__ p =
            (const float4*)inb + (((w << 5) + rg) << 2);

        #pragma unroll 1
        for (int k = 0; k < 8; ++k) {
            const float4 f0 = p[0];
            const float4 f1 = p[1];
            const float4 f2 = p[2];
            const float4 f3 = p[3];
            p += 1024;                          // 256 rows * 4 float4
            if (pass) {
                float dx = f0.x * wv0.x + f1.x * wv1.x + f2.x * wv2.x + f3.x * wv3.x;
                float dy = f0.y * wv0.y + f1.y * wv1.y + f2.y * wv2.y + f3.y * wv3.y;
                float dz = f0.z * wv0.z + f1.z * wv1.z + f2.z * wv2.z + f3.z * wv3.z;
                float dw = f0.w * wv0.w + f1.w * wv1.w + f2.w * wv2.w + f3.w * wv3.w;
                const float e = __expf((dx + dy) + (dz + dw));  // |logit| small
                S += e;
                x0.x += e * f0.x; x0.y += e * f0.y; x0.z += e * f0.z; x0.w += e * f0.w;
                x1.x += e * f1.x; x1.y += e * f1.y; x1.z += e * f1.z; x1.w += e * f1.w;
                x2.x += e * f2.x; x2.y += e * f2.y; x2.z += e * f2.z; x2.w += e * f2.w;
                x3.x += e * f3.x; x3.y += e * f3.y; x3.z += e * f3.z; x3.w += e * f3.w;
            } else {                            // uniform pass: e = 1
                x0.x += f0.x; x0.y += f0.y; x0.z += f0.z; x0.w += f0.w;
                x1.x += f1.x; x1.y += f1.y; x1.z += f1.z; x1.w += f1.w;
                x2.x += f2.x; x2.y += f2.y; x2.z += f2.z; x2.w += f2.w;
                x3.x += f3.x; x3.y += f3.y; x3.z += f3.z; x3.w += f3.w;
            }
        }
        if (!pass) S = 8.f;                     // 8 rows/lane, e=1

        // butterfly over the 32 lanes sharing this mi (masks 2..32)
        #pragma unroll
        for (int mask = 2; mask <= 32; mask <<= 1) {
            S    += __shfl_xor(S,    mask);
            x0.x += __shfl_xor(x0.x, mask); x0.y += __shfl_xor(x0.y, mask);
            x0.z += __shfl_xor(x0.z, mask); x0.w += __shfl_xor(x0.w, mask);
            x1.x += __shfl_xor(x1.x, mask); x1.y += __shfl_xor(x1.y, mask);
            x1.z += __shfl_xor(x1.z, mask); x1.w += __shfl_xor(x1.w, mask);
            x2.x += __shfl_xor(x2.x, mask); x2.y += __shfl_xor(x2.y, mask);
            x2.z += __shfl_xor(x2.z, mask); x2.w += __shfl_xor(x2.w, mask);
            x3.x += __shfl_xor(x3.x, mask); x3.y += __shfl_xor(x3.y, mask);
            x3.z += __shfl_xor(x3.z, mask); x3.w += __shfl_xor(x3.w, mask);
        }
        if (l < 2) {                            // l == mi
            float* rp = &red[w * 34 + l * 17];
            rp[0]  = S;
            rp[1]  = x0.x; rp[2]  = x0.y; rp[3]  = x0.z; rp[4]  = x0.w;
            rp[5]  = x1.x; rp[6]  = x1.y; rp[7]  = x1.z; rp[8]  = x1.w;
            rp[9]  = x2.x; rp[10] = x2.y; rp[11] = x2.z; rp[12] = x2.w;
            rp[13] = x3.x; rp[14] = x3.y; rp[15] = x3.z; rp[16] = x3.w;
        }
        __syncthreads();
        if (tid < 34) {
            float a = 0.f;
            #pragma unroll
            for (int w2 = 0; w2 < 8; ++w2) a += red[w2 * 34 + tid];
            fin[tid] = a;
        }
        __syncthreads();

        // tail: s = (xc/S) @ W_m, v = squash(s); update cum or write out
        if (tid < 32) {
            const int tmi = tid >> 4;
            const int tc  = tid & 15;
            const float rS = 1.f / fin[tmi * 17];
            float s = 0.f;
            #pragma unroll
            for (int d = 0; d < 16; ++d)
                s += fin[tmi * 17 + 1 + d] * w_lds[d * 33 + (tmi << 4) + tc];
            s *= rS;
            float n2 = s * s;
            n2 += __shfl_xor(n2, 1);
            n2 += __shfl_xor(n2, 2);
            n2 += __shfl_xor(n2, 4);
            n2 += __shfl_xor(n2, 8);
            const float nr = sqrtf(n2);
            const float v  = s * (n2 / (1.f + n2)) / (nr + 1e-7f);
            if (pass < 2) {
                float wvv = 0.f;                // wv[d=tc] for capsule tmi
                #pragma unroll
                for (int c2 = 0; c2 < 16; ++c2)
                    wvv += w_lds[tc * 33 + (tmi << 4) + c2] * __shfl(v, (tmi << 4) + c2);
                if (pass == 0) cum[(tmi << 4) + tc] = wvv;
                else           cum[(tmi << 4) + tc] += wvv;
            } else {
                out[((size_t)b << 9) + ((m0 + tmi) << 4) + tc] = v;
            }
        }
        __syncthreads();
    }
}

extern "C" void kernel_launch(void* const* d_in, const int* in_sizes, int n_in,
                              void* d_out, int out_size, void* d_ws, size_t ws_size,
                              hipStream_t stream) {
    (void)in_sizes; (void)n_in; (void)d_ws; (void)ws_size; (void)out_size;
    const float* in = (const float*)d_in[0];
    const float* W  = (const float*)d_in[1];
    float* out = (float*)d_out;
    hipLaunchKernelGGL(capsule_routing_kernel, dim3(1024), dim3(TPB), 0, stream,
                       in, W, out);
}

// Round 7
// 83.214 us; speedup vs baseline: 1.6542x; 1.2041x over previous
//
#include <hip/hip_runtime.h>
#include <math.h>

// CapsuleLayer dynamic routing, factored (u_hat never materialized):
//   s[b,m,:] = ((Sum_n e_n in[b,n,:]) / Sum_n e_n) @ W[:,m,:],  e_n = exp(logit)
//   logit linear in per-pass wv updates -> cumulative wv in LDS, no per-n state.
//   Pass 0 (uniform softmax) = plain column sum, S = 2048.
//
// R5 lesson (measured): vL1D processes ~1 line/cyc/CU; row-per-lane float4
// reads touched each 64B line 4x -> ~41 us of L1 occupancy = the kernel.
// R6: DENSE reads. Lane l = (row l>>2, dim-quarter l&3), addr = base + l*16B:
// one instr = 64 distinct lines, each touched once -> 4x fewer L1 cycles.
// R6 BUG (fixed here): row_shr moves data to HIGHER lanes (sums land in lanes
// 12..15 — why rocPRIM follows with row_bcast:15). Harvesting at lanes 0..3
// needs row_shl:4/8 (0x104/0x108): lane i += lane i+4, i+8 -> lanes 0..3 hold
// the 4-group sums; xor16/xor32 are symmetric and finish the 16-lane sum.
// Grid 1024 = 64 b x 16 m-pairs, 512 thr; launch_bounds (512,4) -> 64-reg
// budget (compiler rule: VGPR = 256/min_waves, measured R1-R5); actual ~52
// regs -> HW runs 8 waves/EU.  b = bx&63 pins batch b to XCD b%8.

#define TPB 512

// x + dpp_shuffled(x); bound_ctrl=true -> out-of-pattern lanes contribute 0
#define DPP_ADDF(x, ctrl) \
    ((x) + __int_as_float(__builtin_amdgcn_update_dpp( \
        0, __float_as_int(x), (ctrl), 0xF, 0xF, true)))
// quad_perm xor1 = 0xB1, xor2 = 0x4E; row_shl:4 = 0x104, row_shl:8 = 0x108

__global__ __launch_bounds__(TPB, 4)
void capsule_routing_kernel(const float* __restrict__ in,
                            const float* __restrict__ W,
                            float* __restrict__ out)
{
    __shared__ float red[8 * 34];    // [wave][m*17 + {S, xc[16]}]
    __shared__ float fin[34];
    __shared__ float cum[32];        // cumulative wv[mi][d]
    __shared__ float w_lds[16 * 33]; // W[d][mi*16+c], stride 33

    const int tid = threadIdx.x;
    const int w   = tid >> 6;
    const int l   = tid & 63;
    const int c4  = l & 3;           // dims 4*c4 .. 4*c4+3 of row (l>>2)
    const int b   = blockIdx.x & 63;
    const int m0  = (blockIdx.x >> 6) << 1;

    // dense: lane l reads float4 #(w*1024 + g*64 + l)  (1 KB per wave-instr)
    const float4* __restrict__ inb4 =
        (const float4*)(in + ((size_t)b << 15)) + ((w << 10) + l);

    {   // stage W[:, m0:m0+2, :] -> LDS
        const int d = tid >> 5, r = tid & 31;
        w_lds[d * 33 + r] = W[(d << 9) + (m0 << 4) + r];
    }
    __syncthreads();

    for (int pass = 0; pass < 3; ++pass) {
        float wv0[4], wv1[4];
        if (pass) {
            #pragma unroll
            for (int j = 0; j < 4; ++j) {
                wv0[j] = cum[(c4 << 2) + j];
                wv1[j] = cum[16 + (c4 << 2) + j];
            }
        }

        float S0 = 0.f, S1 = 0.f;
        float x0[4] = {0.f, 0.f, 0.f, 0.f};
        float x1[4] = {0.f, 0.f, 0.f, 0.f};

        #pragma unroll 4
        for (int g = 0; g < 16; ++g) {
            const float4 f = inb4[g << 6];
            if (pass) {
                float d0 = f.x*wv0[0] + f.y*wv0[1] + f.z*wv0[2] + f.w*wv0[3];
                float d1 = f.x*wv1[0] + f.y*wv1[1] + f.z*wv1[2] + f.w*wv1[3];
                d0 = DPP_ADDF(d0, 0xB1); d0 = DPP_ADDF(d0, 0x4E);  // quad-sum
                d1 = DPP_ADDF(d1, 0xB1); d1 = DPP_ADDF(d1, 0x4E);
                const float e0 = __expf(d0);   // quad-uniform
                const float e1 = __expf(d1);
                S0 += e0; S1 += e1;
                x0[0] += e0*f.x; x0[1] += e0*f.y; x0[2] += e0*f.z; x0[3] += e0*f.w;
                x1[0] += e1*f.x; x1[1] += e1*f.y; x1[2] += e1*f.z; x1[3] += e1*f.w;
            } else {                            // e = 1: xc independent of m
                x0[0] += f.x; x0[1] += f.y; x0[2] += f.z; x0[3] += f.w;
            }
        }
        if (!pass) {
            #pragma unroll
            for (int j = 0; j < 4; ++j) x1[j] = x0[j];
        }

        // reduce over the 16 lanes sharing c4:
        // row_shl:4 + row_shl:8 (VALU DPP; lanes 0..3 of each row-of-16 get
        // the 4-group sums) then xor16 + xor32 (DS, symmetric) -> lanes 0..3
        // hold the full 16-lane sums.
        float vals[10] = { x0[0], x0[1], x0[2], x0[3],
                           x1[0], x1[1], x1[2], x1[3], S0, S1 };
        #pragma unroll
        for (int v = 0; v < 10; ++v) {
            float x = vals[v];
            x = DPP_ADDF(x, 0x104);   // lane i += lane i+4
            x = DPP_ADDF(x, 0x108);   // lane i += lane i+8
            x += __shfl_xor(x, 16);
            x += __shfl_xor(x, 32);
            vals[v] = x;
        }
        if (l < 4) {                 // lane index == c4 here
            float* rp = &red[w * 34];
            #pragma unroll
            for (int j = 0; j < 4; ++j) {
                rp[1 + (c4 << 2) + j]      = vals[j];       // m0 xc dims
                rp[18 + (c4 << 2) + j]     = vals[4 + j];   // m1 xc dims
            }
            if (l == 0) {
                rp[0]  = pass ? vals[8] : 256.f;            // S per wave
                rp[17] = pass ? vals[9] : 256.f;
            }
        }
        __syncthreads();
        if (tid < 34) {
            float a = 0.f;
            #pragma unroll
            for (int w2 = 0; w2 < 8; ++w2) a += red[w2 * 34 + tid];
            fin[tid] = a;
        }
        __syncthreads();

        // tail: s = (xc/S) @ W_m, v = squash(s); update cum or write out
        if (tid < 32) {
            const int tmi = tid >> 4;
            const int tc  = tid & 15;
            const float rS = 1.f / fin[tmi * 17];
            float s = 0.f;
            #pragma unroll
            for (int d = 0; d < 16; ++d)
                s += fin[tmi * 17 + 1 + d] * w_lds[d * 33 + (tmi << 4) + tc];
            s *= rS;
            float n2 = s * s;
            n2 += __shfl_xor(n2, 1);
            n2 += __shfl_xor(n2, 2);
            n2 += __shfl_xor(n2, 4);
            n2 += __shfl_xor(n2, 8);
            const float nr = sqrtf(n2);
            const float v  = s * (n2 / (1.f + n2)) / (nr + 1e-7f);
            if (pass < 2) {
                float wvv = 0.f;                // wv[d=tc] for capsule tmi
                #pragma unroll
                for (int c2 = 0; c2 < 16; ++c2)
                    wvv += w_lds[tc * 33 + (tmi << 4) + c2] * __shfl(v, (tmi << 4) + c2);
                if (pass == 0) cum[(tmi << 4) + tc] = wvv;
                else           cum[(tmi << 4) + tc] += wvv;
            } else {
                out[((size_t)b << 9) + ((m0 + tmi) << 4) + tc] = v;
            }
        }
        __syncthreads();
    }
}

extern "C" void kernel_launch(void* const* d_in, const int* in_sizes, int n_in,
                              void* d_out, int out_size, void* d_ws, size_t ws_size,
                              hipStream_t stream) {
    (void)in_sizes; (void)n_in; (void)d_ws; (void)ws_size; (void)out_size;
    const float* in = (const float*)d_in[0];
    const float* W  = (const float*)d_in[1];
    float* out = (float*)d_out;
    hipLaunchKernelGGL(capsule_routing_kernel, dim3(1024), dim3(TPB), 0, stream,
                       in, W, out);
}

// Round 8
// 81.375 us; speedup vs baseline: 1.6916x; 1.0226x over previous
//
#include <hip/hip_runtime.h>
#include <math.h>

// CapsuleLayer dynamic routing, factored (u_hat never materialized):
//   s[b,m,:] = ((Sum_n e_n in[b,n,:]) / Sum_n e_n) @ W[:,m,:],  e_n = exp(logit)
//   logit linear in per-pass wv updates -> cumulative wv in LDS, no per-n state.
//   Pass 0 (uniform softmax) = plain column sum, per-wave S = 256.
//
// Evidence so far (R5/R7): wall ~= poorly-overlapped sum of VALU-issue (~9us)
// + L1 line-touches (~1 line/cyc/CU; 4 blk/CU x 3 passes x 2048 lines ~10us)
// + DS-pipe (~5us) + tails. R8 levers:
//  (1) 4 m's/block, grid 512 = 2 blocks/CU -> L1 re-reads halved (~5us).
//  (2) float2 ext-vector math -> v_pk_fma_f32 packing on dot + xc.
//  (3) launch_bounds(512,2): 128-reg budget (compiler rule VGPR=256/minwaves,
//      measured R1-R5). Grid limits residency to 16 waves/CU regardless, so
//      the bigger budget sacrifices nothing and guarantees no spill.
// Dense reads (R6): lane = (row l>>2, dim-quarter l&3) -> one instr = 64
// distinct 64B lines. Quad dot-sum via DPP quad_perm (VALU pipe); 16-lane
// harvest via row_shl:4/8 (sums land in lanes 0..3 — R6 bug fixed in R7) then
// symmetric xor16/xor32.  b = bx&63 pins batch b's 8 blocks to XCD b%8.

#define TPB 512

typedef float vf2 __attribute__((ext_vector_type(2)));

// x + dpp_shuffled(x); bound_ctrl=true -> out-of-pattern lanes contribute 0
#define DPP_ADDF(x, ctrl) \
    ((x) + __int_as_float(__builtin_amdgcn_update_dpp( \
        0, __float_as_int(x), (ctrl), 0xF, 0xF, true)))
// quad_perm xor1 = 0xB1, xor2 = 0x4E; row_shl:4 = 0x104, row_shl:8 = 0x108

__global__ __launch_bounds__(TPB, 2)
void capsule_routing_kernel(const float* __restrict__ in,
                            const float* __restrict__ W,
                            float* __restrict__ out)
{
    __shared__ float red[8 * 68];    // [wave][m*17 + {S, xc[16]}]
    __shared__ float fin[68];
    __shared__ float cum[64];        // cumulative wv[mi][d]
    __shared__ float w_lds[16 * 65]; // W[d][mi*16+c], stride 65

    const int tid = threadIdx.x;
    const int w   = tid >> 6;
    const int l   = tid & 63;
    const int c4  = l & 3;           // dims 4*c4..4*c4+3 of row (l>>2)
    const int b   = blockIdx.x & 63;
    const int m0  = (blockIdx.x >> 6) << 2;   // 8 m-quads

    // dense: lane l reads float4 #(w*1024 + g*64 + l)  (1 KB per wave-instr)
    const float4* __restrict__ inb4 =
        (const float4*)(in + ((size_t)b << 15)) + ((w << 10) + l);

    // stage W[:, m0:m0+4, :] (1024 floats) -> LDS, row stride 65
    #pragma unroll
    for (int k = 0; k < 2; ++k) {
        const int idx = tid + k * TPB;
        const int d = idx >> 6, r = idx & 63;
        w_lds[d * 65 + r] = W[(d << 9) + (m0 << 4) + r];
    }
    __syncthreads();

    for (int pass = 0; pass < 3; ++pass) {
        vf2 wva[4], wvb[4];
        if (pass) {
            const float4* cp = (const float4*)cum;   // 16B-aligned per lane
            #pragma unroll
            for (int m = 0; m < 4; ++m) {
                const float4 q = cp[(m << 2) + c4];  // cum[m*16 + c4*4 ..+3]
                wva[m].x = q.x; wva[m].y = q.y;
                wvb[m].x = q.z; wvb[m].y = q.w;
            }
        }

        vf2 xa[4], xb[4];
        float S[4];
        #pragma unroll
        for (int m = 0; m < 4; ++m) {
            xa[m].x = 0.f; xa[m].y = 0.f;
            xb[m].x = 0.f; xb[m].y = 0.f;
            S[m] = 0.f;
        }

        #pragma unroll 2
        for (int g = 0; g < 16; ++g) {
            const float4 f = inb4[g << 6];
            vf2 fa, fb;
            fa.x = f.x; fa.y = f.y; fb.x = f.z; fb.y = f.w;
            if (pass) {
                #pragma unroll
                for (int m = 0; m < 4; ++m) {
                    vf2 t = fa * wva[m] + fb * wvb[m];   // pk_mul + pk_fma
                    float d = t.x + t.y;
                    d = DPP_ADDF(d, 0xB1);               // quad-sum
                    d = DPP_ADDF(d, 0x4E);
                    const float e = __expf(d);           // quad-uniform
                    S[m] += e;
                    xa[m] += fa * e;                     // pk_fma (splat e)
                    xb[m] += fb * e;
                }
            } else {                                     // e = 1, m-independent
                xa[0] += fa; xb[0] += fb;
            }
        }
        if (!pass) {
            #pragma unroll
            for (int m = 1; m < 4; ++m) { xa[m] = xa[0]; xb[m] = xb[0]; }
        }

        // reduce over the 16 lanes sharing c4 (16 distinct rows each):
        // row_shl:4 + row_shl:8 (VALU DPP -> lanes 0..3 hold 4-group sums),
        // then xor16 + xor32 (DS, symmetric) -> lanes 0..3 full sums.
        float vals[20] = { xa[0].x, xa[0].y, xb[0].x, xb[0].y,
                           xa[1].x, xa[1].y, xb[1].x, xb[1].y,
                           xa[2].x, xa[2].y, xb[2].x, xb[2].y,
                           xa[3].x, xa[3].y, xb[3].x, xb[3].y,
                           S[0], S[1], S[2], S[3] };
        #pragma unroll
        for (int v = 0; v < 20; ++v) {
            float x = vals[v];
            x = DPP_ADDF(x, 0x104);   // lane i += lane i+4
            x = DPP_ADDF(x, 0x108);   // lane i += lane i+8
            x += __shfl_xor(x, 16);
            x += __shfl_xor(x, 32);
            vals[v] = x;
        }
        if (l < 4) {                  // lane index == c4
            float* rp = &red[w * 68];
            #pragma unroll
            for (int m = 0; m < 4; ++m) {
                #pragma unroll
                for (int j = 0; j < 4; ++j)
                    rp[m * 17 + 1 + (c4 << 2) + j] = vals[(m << 2) + j];
            }
            if (l == 0) {
                #pragma unroll
                for (int m = 0; m < 4; ++m)
                    rp[m * 17] = pass ? vals[16 + m] : 256.f;
            }
        }
        __syncthreads();
        if (tid < 68) {
            float a = 0.f;
            #pragma unroll
            for (int w2 = 0; w2 < 8; ++w2) a += red[w2 * 68 + tid];
            fin[tid] = a;
        }
        __syncthreads();

        // tail on wave 0: s = (xc/S) @ W_m, v = squash(s); cum update or out
        if (tid < 64) {
            const int tmi = tid >> 4;
            const int tc  = tid & 15;
            const float rS = 1.f / fin[tmi * 17];
            float s = 0.f;
            #pragma unroll
            for (int d = 0; d < 16; ++d)
                s += fin[tmi * 17 + 1 + d] * w_lds[d * 65 + (tmi << 4) + tc];
            s *= rS;
            float n2 = s * s;
            n2 += __shfl_xor(n2, 1);
            n2 += __shfl_xor(n2, 2);
            n2 += __shfl_xor(n2, 4);
            n2 += __shfl_xor(n2, 8);
            const float nr = sqrtf(n2);
            const float v  = s * (n2 / (1.f + n2)) / (nr + 1e-7f);
            if (pass < 2) {
                float wvv = 0.f;                 // wv[d=tc] for capsule tmi
                #pragma unroll
                for (int c2 = 0; c2 < 16; ++c2)
                    wvv += w_lds[tc * 65 + (tmi << 4) + c2] * __shfl(v, (tmi << 4) + c2);
                if (pass == 0) cum[(tmi << 4) + tc] = wvv;
                else           cum[(tmi << 4) + tc] += wvv;
            } else {
                out[((size_t)b << 9) + ((m0 + tmi) << 4) + tc] = v;
            }
        }
        __syncthreads();
    }
}

extern "C" void kernel_launch(void* const* d_in, const int* in_sizes, int n_in,
                              void* d_out, int out_size, void* d_ws, size_t ws_size,
                              hipStream_t stream) {
    (void)in_sizes; (void)n_in; (void)d_ws; (void)ws_size; (void)out_size;
    const float* in = (const float*)d_in[0];
    const float* W  = (const float*)d_in[1];
    float* out = (float*)d_out;
    hipLaunchKernelGGL(capsule_routing_kernel, dim3(512), dim3(TPB), 0, stream,
                       in, W, out);
}